// Round 1
// baseline (642.124 us; speedup 1.0000x reference)
//
#include <hip/hip_runtime.h>

#define N_NODES 50000
#define FEAT 256
#define HID 64
#define NEDGE 800000
#define SCAN_CHUNK 2048
#define NB_SCAN 25  // ceil(50000/2048)

// ---------------- embed: r0 = relu(x @ We)  [50000,256]@[256,64] ----------------
// block 256 = 4 waves; wave handles 4 rows; block 16 rows; grid 3125
__global__ __launch_bounds__(256) void embed_kernel(const float* __restrict__ x,
        const float* __restrict__ we, float* __restrict__ r0) {
    const int lane = threadIdx.x & 63;
    const int wid  = threadIdx.x >> 6;
    const int row0 = blockIdx.x * 16 + wid * 4;
    const float* xp = x + (size_t)row0 * FEAT;
    float a[4] = {0.f, 0.f, 0.f, 0.f};
    for (int k = 0; k < FEAT; k += 4) {
        float w0 = we[(k+0)*HID + lane];
        float w1 = we[(k+1)*HID + lane];
        float w2 = we[(k+2)*HID + lane];
        float w3 = we[(k+3)*HID + lane];
#pragma unroll
        for (int r = 0; r < 4; ++r) {
            float4 xv = *(const float4*)(xp + (size_t)r * FEAT + k);
            a[r] += xv.x*w0 + xv.y*w1 + xv.z*w2 + xv.w*w3;
        }
    }
    size_t ob = (size_t)row0 * HID + lane;
#pragma unroll
    for (int r = 0; r < 4; ++r)
        r0[ob + (size_t)r * HID] = fmaxf(a[r], 0.f);
}

// ---------------- CSR build ----------------
__global__ __launch_bounds__(256) void hist_kernel(const int* __restrict__ rows,
        int* __restrict__ cnt) {
    int e = blockIdx.x * 256 + threadIdx.x;
    if (e < NEDGE) atomicAdd(&cnt[rows[e]], 1);
}

__global__ __launch_bounds__(256) void scan_a(const int* __restrict__ cnt,
        int* __restrict__ bsum) {
    __shared__ int sd[256];
    const int t = threadIdx.x;
    const int base = blockIdx.x * SCAN_CHUNK + t * 8;
    int s = 0;
#pragma unroll
    for (int i = 0; i < 8; ++i) {
        int idx = base + i;
        s += (idx < N_NODES) ? cnt[idx] : 0;
    }
    sd[t] = s; __syncthreads();
    for (int off = 128; off > 0; off >>= 1) {
        if (t < off) sd[t] += sd[t + off];
        __syncthreads();
    }
    if (t == 0) bsum[blockIdx.x] = sd[0];
}

__global__ __launch_bounds__(64) void scan_b(int* __restrict__ bsum,
        int* __restrict__ rowPtr) {
    if (threadIdx.x == 0) {
        int run = 0;
        for (int b = 0; b < NB_SCAN; ++b) {
            int v = bsum[b];
            bsum[b] = run;   // becomes block offset
            run += v;
        }
        rowPtr[N_NODES] = run;
    }
}

__global__ __launch_bounds__(256) void scan_c(const int* __restrict__ cnt,
        const int* __restrict__ boff, int* __restrict__ rowPtr) {
    __shared__ int sd[256];
    const int t = threadIdx.x;
    const int base = blockIdx.x * SCAN_CHUNK + t * 8;
    int v[8];
    int s = 0;
#pragma unroll
    for (int i = 0; i < 8; ++i) {
        int idx = base + i;
        v[i] = (idx < N_NODES) ? cnt[idx] : 0;
        s += v[i];
    }
    sd[t] = s; __syncthreads();
    for (int off = 1; off < 256; off <<= 1) {
        int add = (t >= off) ? sd[t - off] : 0;
        __syncthreads();
        sd[t] += add;
        __syncthreads();
    }
    int run = boff[blockIdx.x] + (sd[t] - s);  // exclusive prefix for this thread
#pragma unroll
    for (int i = 0; i < 8; ++i) {
        int idx = base + i;
        if (idx < N_NODES) rowPtr[idx] = run;
        run += v[i];
    }
}

__global__ __launch_bounds__(256) void scatter_kernel(const int* __restrict__ rows,
        const int* __restrict__ cols, const float* __restrict__ vals,
        const int* __restrict__ rowPtr, int* __restrict__ fill,
        int* __restrict__ colS, float* __restrict__ valS) {
    int e = blockIdx.x * 256 + threadIdx.x;
    if (e < NEDGE) {
        int r = rows[e];
        int p = rowPtr[r] + atomicAdd(&fill[r], 1);
        colS[p] = cols[e];
        valS[p] = vals[e];
    }
}

// ---------------- SpMM (CSR, one wave per row, lane = feature col) ----------------
__global__ __launch_bounds__(256) void spmm64_kernel(const int* __restrict__ colS,
        const float* __restrict__ valS, const int* __restrict__ rowPtr,
        const float* __restrict__ src, float* __restrict__ dst) {
    const int lane = threadIdx.x & 63;
    const int row  = (int)((blockIdx.x * 256u + threadIdx.x) >> 6);
    const int beg = rowPtr[row], end = rowPtr[row + 1];
    float acc = 0.f;
    int i = beg;
    for (; i + 4 <= end; i += 4) {
        int c0 = colS[i], c1 = colS[i+1], c2 = colS[i+2], c3 = colS[i+3];
        float v0 = valS[i], v1 = valS[i+1], v2 = valS[i+2], v3 = valS[i+3];
        float g0 = src[(size_t)c0*HID + lane];
        float g1 = src[(size_t)c1*HID + lane];
        float g2 = src[(size_t)c2*HID + lane];
        float g3 = src[(size_t)c3*HID + lane];
        acc += v0*g0; acc += v1*g1; acc += v2*g2; acc += v3*g3;
    }
    for (; i < end; ++i)
        acc += valS[i] * src[(size_t)colS[i]*HID + lane];
    dst[(size_t)row*HID + lane] = acc;
}

// t = adj@s fused with r1cat = relu(concat[s-r0, t-s-r0])
__global__ __launch_bounds__(256) void spmm64f_kernel(const int* __restrict__ colS,
        const float* __restrict__ valS, const int* __restrict__ rowPtr,
        const float* __restrict__ s, const float* __restrict__ r0,
        float* __restrict__ r1c) {
    const int lane = threadIdx.x & 63;
    const int row  = (int)((blockIdx.x * 256u + threadIdx.x) >> 6);
    const int beg = rowPtr[row], end = rowPtr[row + 1];
    float acc = 0.f;
    int i = beg;
    for (; i + 4 <= end; i += 4) {
        int c0 = colS[i], c1 = colS[i+1], c2 = colS[i+2], c3 = colS[i+3];
        float v0 = valS[i], v1 = valS[i+1], v2 = valS[i+2], v3 = valS[i+3];
        float g0 = s[(size_t)c0*HID + lane];
        float g1 = s[(size_t)c1*HID + lane];
        float g2 = s[(size_t)c2*HID + lane];
        float g3 = s[(size_t)c3*HID + lane];
        acc += v0*g0; acc += v1*g1; acc += v2*g2; acc += v3*g3;
    }
    for (; i < end; ++i)
        acc += valS[i] * s[(size_t)colS[i]*HID + lane];
    float sv = s[(size_t)row*HID + lane];
    float rv = r0[(size_t)row*HID + lane];
    r1c[(size_t)row*128 + lane]      = fmaxf(sv - rv, 0.f);
    r1c[(size_t)row*128 + 64 + lane] = fmaxf(acc - sv - rv, 0.f);
}

__global__ __launch_bounds__(256) void spmm128_kernel(const int* __restrict__ colS,
        const float* __restrict__ valS, const int* __restrict__ rowPtr,
        const float* __restrict__ src, float* __restrict__ dst) {
    const int lane = threadIdx.x & 63;
    const int row  = (int)((blockIdx.x * 256u + threadIdx.x) >> 6);
    const int beg = rowPtr[row], end = rowPtr[row + 1];
    float a0 = 0.f, a1 = 0.f;
    int i = beg;
    for (; i + 2 <= end; i += 2) {
        int c0 = colS[i], c1 = colS[i+1];
        float v0 = valS[i], v1 = valS[i+1];
        const float* s0 = src + (size_t)c0 * 128;
        const float* s1 = src + (size_t)c1 * 128;
        float g00 = s0[lane], g01 = s0[64 + lane];
        float g10 = s1[lane], g11 = s1[64 + lane];
        a0 += v0*g00; a1 += v0*g01;
        a0 += v1*g10; a1 += v1*g11;
    }
    if (i < end) {
        int c = colS[i]; float v = valS[i];
        a0 += v * src[(size_t)c*128 + lane];
        a1 += v * src[(size_t)c*128 + 64 + lane];
    }
    dst[(size_t)row*128 + lane]      = a0;
    dst[(size_t)row*128 + 64 + lane] = a1;
}

// t2 = adj@s2 fused with r2cat = relu(concat[s2-r1, t2-s2-r1])  (widths 128 -> 256)
__global__ __launch_bounds__(256) void spmm128f_kernel(const int* __restrict__ colS,
        const float* __restrict__ valS, const int* __restrict__ rowPtr,
        const float* __restrict__ s2, const float* __restrict__ r1,
        float* __restrict__ r2c) {
    const int lane = threadIdx.x & 63;
    const int row  = (int)((blockIdx.x * 256u + threadIdx.x) >> 6);
    const int beg = rowPtr[row], end = rowPtr[row + 1];
    float a0 = 0.f, a1 = 0.f;
    int i = beg;
    for (; i + 2 <= end; i += 2) {
        int c0 = colS[i], c1 = colS[i+1];
        float v0 = valS[i], v1 = valS[i+1];
        const float* s0 = s2 + (size_t)c0 * 128;
        const float* s1 = s2 + (size_t)c1 * 128;
        float g00 = s0[lane], g01 = s0[64 + lane];
        float g10 = s1[lane], g11 = s1[64 + lane];
        a0 += v0*g00; a1 += v0*g01;
        a0 += v1*g10; a1 += v1*g11;
    }
    if (i < end) {
        int c = colS[i]; float v = valS[i];
        a0 += v * s2[(size_t)c*128 + lane];
        a1 += v * s2[(size_t)c*128 + 64 + lane];
    }
    float s0v = s2[(size_t)row*128 + lane];
    float s1v = s2[(size_t)row*128 + 64 + lane];
    float r0v = r1[(size_t)row*128 + lane];
    float r1v = r1[(size_t)row*128 + 64 + lane];
    size_t ob = (size_t)row * 256 + lane;
    r2c[ob]        = fmaxf(s0v - r0v, 0.f);
    r2c[ob + 64]   = fmaxf(s1v - r1v, 0.f);
    r2c[ob + 128]  = fmaxf(a0 - s0v - r0v, 0.f);
    r2c[ob + 192]  = fmaxf(a1 - s1v - r1v, 0.f);
}

// ---------------- classify + softmax ----------------
// virtual concat [r0(64) | r1cat(128) | r2cat(256)] @ Wc[448,64], then row softmax.
// block 256 = 4 waves; wave handles 4 rows (lane = class col); grid 3125
__global__ __launch_bounds__(256) void classify_kernel(const float* __restrict__ r0,
        const float* __restrict__ r1, const float* __restrict__ r2,
        const float* __restrict__ wc, float* __restrict__ out) {
    const int lane = threadIdx.x & 63;
    const int wid  = threadIdx.x >> 6;
    const int row0 = blockIdx.x * 16 + wid * 4;
    float a[4] = {0.f, 0.f, 0.f, 0.f};

    {   // k 0..63 from r0
        const float* p = r0 + (size_t)row0 * 64;
        for (int k = 0; k < 64; k += 4) {
            float w0 = wc[(k+0)*64 + lane];
            float w1 = wc[(k+1)*64 + lane];
            float w2 = wc[(k+2)*64 + lane];
            float w3 = wc[(k+3)*64 + lane];
#pragma unroll
            for (int r = 0; r < 4; ++r) {
                float4 xv = *(const float4*)(p + (size_t)r * 64 + k);
                a[r] += xv.x*w0 + xv.y*w1 + xv.z*w2 + xv.w*w3;
            }
        }
    }
    {   // k 64..191 from r1cat
        const float* p  = r1 + (size_t)row0 * 128;
        const float* wp = wc + 64 * 64;
        for (int k = 0; k < 128; k += 4) {
            float w0 = wp[(k+0)*64 + lane];
            float w1 = wp[(k+1)*64 + lane];
            float w2 = wp[(k+2)*64 + lane];
            float w3 = wp[(k+3)*64 + lane];
#pragma unroll
            for (int r = 0; r < 4; ++r) {
                float4 xv = *(const float4*)(p + (size_t)r * 128 + k);
                a[r] += xv.x*w0 + xv.y*w1 + xv.z*w2 + xv.w*w3;
            }
        }
    }
    {   // k 192..447 from r2cat
        const float* p  = r2 + (size_t)row0 * 256;
        const float* wp = wc + 192 * 64;
        for (int k = 0; k < 256; k += 4) {
            float w0 = wp[(k+0)*64 + lane];
            float w1 = wp[(k+1)*64 + lane];
            float w2 = wp[(k+2)*64 + lane];
            float w3 = wp[(k+3)*64 + lane];
#pragma unroll
            for (int r = 0; r < 4; ++r) {
                float4 xv = *(const float4*)(p + (size_t)r * 256 + k);
                a[r] += xv.x*w0 + xv.y*w1 + xv.z*w2 + xv.w*w3;
            }
        }
    }

#pragma unroll
    for (int r = 0; r < 4; ++r) {
        float m = a[r];
        for (int o = 32; o > 0; o >>= 1) m = fmaxf(m, __shfl_xor(m, o));
        float e = __expf(a[r] - m);
        float ssum = e;
        for (int o = 32; o > 0; o >>= 1) ssum += __shfl_xor(ssum, o);
        out[(size_t)(row0 + r) * 64 + lane] = e / ssum;
    }
}

extern "C" void kernel_launch(void* const* d_in, const int* in_sizes, int n_in,
                              void* d_out, int out_size, void* d_ws, size_t ws_size,
                              hipStream_t stream) {
    const float* x    = (const float*)d_in[0];
    const int*   erow = (const int*)d_in[1];
    const int*   ecol = (const int*)d_in[2];
    const float* eval = (const float*)d_in[3];
    const float* we   = (const float*)d_in[4];
    const float* wc   = (const float*)d_in[5];
    float* out = (float*)d_out;

    char* w = (char*)d_ws;
    size_t off = 0;
    auto take = [&](size_t bytes) {
        char* p = w + off;
        off += (bytes + 255) & ~(size_t)255;
        return p;
    };
    float* r0     = (float*)take((size_t)N_NODES * 64 * 4);
    float* sbuf   = (float*)take((size_t)N_NODES * 128 * 4);  // s (w64) then s2 (w128)
    float* r1c    = (float*)take((size_t)N_NODES * 128 * 4);
    float* r2c    = (float*)take((size_t)N_NODES * 256 * 4);
    int*   cnt    = (int*)take((size_t)N_NODES * 4);
    int*   rowPtr = (int*)take((size_t)(N_NODES + 1) * 4);
    int*   fill   = (int*)take((size_t)N_NODES * 4);
    int*   bsum   = (int*)take((size_t)NB_SCAN * 4);
    int*   colS   = (int*)take((size_t)NEDGE * 4);
    float* valS   = (float*)take((size_t)NEDGE * 4);
    (void)ws_size; (void)in_sizes; (void)n_in; (void)out_size;

    hipMemsetAsync(cnt,  0, (size_t)N_NODES * 4, stream);
    hipMemsetAsync(fill, 0, (size_t)N_NODES * 4, stream);

    embed_kernel<<<3125, 256, 0, stream>>>(x, we, r0);

    hist_kernel<<<3125, 256, 0, stream>>>(erow, cnt);
    scan_a<<<NB_SCAN, 256, 0, stream>>>(cnt, bsum);
    scan_b<<<1, 64, 0, stream>>>(bsum, rowPtr);
    scan_c<<<NB_SCAN, 256, 0, stream>>>(cnt, bsum, rowPtr);
    scatter_kernel<<<3125, 256, 0, stream>>>(erow, ecol, eval, rowPtr, fill, colS, valS);

    spmm64_kernel <<<12500, 256, 0, stream>>>(colS, valS, rowPtr, r0, sbuf);
    spmm64f_kernel<<<12500, 256, 0, stream>>>(colS, valS, rowPtr, sbuf, r0, r1c);
    spmm128_kernel<<<12500, 256, 0, stream>>>(colS, valS, rowPtr, r1c, sbuf);
    spmm128f_kernel<<<12500, 256, 0, stream>>>(colS, valS, rowPtr, sbuf, r1c, r2c);

    classify_kernel<<<3125, 256, 0, stream>>>(r0, r1c, r2c, wc, out);
}